// Round 14
// baseline (647.316 us; speedup 1.0000x reference)
//
#include <hip/hip_runtime.h>

#define B_  32
#define CL_ 1024
#define QL_ 512
#define D_  256

typedef _Float16 f16;
typedef __attribute__((ext_vector_type(2))) _Float16 f16x2;
typedef __attribute__((ext_vector_type(4))) _Float16 f16x4;
typedef __attribute__((ext_vector_type(8))) _Float16 f16x8;
typedef __attribute__((ext_vector_type(4))) float    f32x4;

// ------- K0: q -> f16 (q_h), qT_h transpose, sqv[b,j] = q.w_q — fused ----
__global__ __launch_bounds__(256) void k0_prep(const float* __restrict__ q,
                                               const float* __restrict__ w_q,
                                               f16* __restrict__ q_h,
                                               f16* __restrict__ qT_h,
                                               float* __restrict__ sqv) {
  __shared__ f16 q_l[64][258];
  int b = blockIdx.y, j0 = blockIdx.x * 64, tid = threadIdx.x;
  int r = tid >> 2, seg = tid & 3;
  const float* qrow = q   + ((size_t)(b * QL_ + j0 + r)) * D_ + seg * 64;
  f16*        qhrow = q_h + ((size_t)(b * QL_ + j0 + r)) * D_ + seg * 64;
  float dot = 0.f;
  #pragma unroll
  for (int u = 0; u < 16; ++u) {
    f32x4 v  = *(const f32x4*)(qrow + 4 * u);
    f32x4 wv = *(const f32x4*)(w_q + seg * 64 + 4 * u);
    f16x4 h;
    h[0] = (f16)v[0]; h[1] = (f16)v[1]; h[2] = (f16)v[2]; h[3] = (f16)v[3];
    *(f16x4*)(&q_l[r][seg * 64 + 4 * u]) = h;
    *(f16x4*)(qhrow + 4 * u) = h;
    dot += v[0]*wv[0] + v[1]*wv[1] + v[2]*wv[2] + v[3]*wv[3];
  }
  dot += __shfl_xor(dot, 1, 64);
  dot += __shfl_xor(dot, 2, 64);
  if (seg == 0) sqv[b * QL_ + j0 + r] = dot;
  __syncthreads();
  f16* qTb = qT_h + (size_t)b * D_ * QL_ + j0;
  #pragma unroll
  for (int s = 0; s < 32; ++s) {
    int e = tid + 256 * s;
    int d = e >> 5, j2 = (e & 31) * 2;
    f16x2 p;
    p[0] = q_l[j2][d];
    p[1] = q_l[j2 + 1][d];
    *(f16x2*)(qTb + (size_t)d * QL_ + j2) = p;
  }
}

// ======================= ABLATION CLONES of R7 k1 ========================
// Each repeats its phase R times (pushes dispatch dur into rocprof top-5).
// Writes go ONLY to out[0:3D] cells later rewritten by the real k1_fused.

// --- front: cw stage + phase A (direct gathers) + softmax + P write ------
__global__ __launch_bounds__(512, 2) void kabl_front(
    const float* __restrict__ c, const f16* __restrict__ q_h,
    const float* __restrict__ sqv, const float* __restrict__ w_c,
    const float* __restrict__ w_cq, float* __restrict__ out)
{
  __shared__ alignas(16) char smem[142848];
  f16 (*cw_t)[264]  = (f16 (*)[264])(smem);
  char* P_b         = smem;
  float* sqv_l = (float*)(smem + 133120);
  float* wcq_l = (float*)(smem + 135168);
  float* wc_l  = (float*)(smem + 136192);
  float* scv_l = (float*)(smem + 137216);
  float (*red)[128] = (float (*)[128])(smem + 137728);
  float* mf = (float*)(smem + 141824);
  float* lf = (float*)(smem + 142336);

  const int tid = threadIdx.x;
  const int w = tid >> 6, l = tid & 63, g = l >> 4, l15 = l & 15;
  const int lin = blockIdx.x, xcd = lin & 7, slot = lin >> 3;
  const int b  = xcd * 4 + (slot >> 3);
  const int i0 = (slot & 7) * 128;

  if (tid < 256) { wcq_l[tid] = w_cq[tid]; wc_l[tid] = w_c[tid]; }
  sqv_l[tid] = sqv[b * QL_ + tid];
  __syncthreads();

  f32x4 acc[8][4];
  #pragma unroll
  for (int fi = 0; fi < 8; ++fi)
    #pragma unroll
    for (int fj = 0; fj < 4; ++fj)
      acc[fi][fj] = (f32x4){0.f,0.f,0.f,0.f};

  #pragma unroll 1
  for (int rep = 0; rep < 3; ++rep) {
    // stage cw_t + scv
    {
      int row = tid >> 2, seg = tid & 3;
      const float* crow = c + (size_t)(b * CL_ + i0 + row) * D_ + seg * 64;
      float dot = 0.f;
      #pragma unroll
      for (int u = 0; u < 16; ++u) {
        f32x4 v  = *(const f32x4*)(crow + 4 * u);
        f32x4 wv = *(const f32x4*)(wcq_l + seg * 64 + 4 * u);
        f32x4 w2 = *(const f32x4*)(wc_l  + seg * 64 + 4 * u);
        f16x4 h;
        h[0] = (f16)(v[0]*wv[0]); h[1] = (f16)(v[1]*wv[1]);
        h[2] = (f16)(v[2]*wv[2]); h[3] = (f16)(v[3]*wv[3]);
        *(f16x4*)(&cw_t[row][seg * 64 + 4 * u]) = h;
        dot += v[0]*w2[0] + v[1]*w2[1] + v[2]*w2[2] + v[3]*w2[3];
      }
      dot += __shfl_xor(dot, 1, 64); dot += __shfl_xor(dot, 2, 64);
      if (seg == 0) scv_l[row] = dot;
    }
    __syncthreads();

    // phase A (direct gathers, R7 pattern); acc accumulates across reps
    const f16* qb = q_h + (size_t)b * QL_ * D_ + (size_t)(64 * w + l15) * D_ + 8 * g;
    #pragma unroll
    for (int dk = 0; dk < 8; ++dk) {
      f16x8 av[8];
      #pragma unroll
      for (int fi = 0; fi < 8; ++fi)
        av[fi] = *(const f16x8*)(&cw_t[16 * fi + l15][dk * 32 + 8 * g]);
      #pragma unroll
      for (int fj = 0; fj < 4; ++fj) {
        f16x8 bf = *(const f16x8*)(qb + (size_t)(16 * fj) * D_ + dk * 32);
        #pragma unroll
        for (int fi = 0; fi < 8; ++fi)
          acc[fi][fj] = __builtin_amdgcn_mfma_f32_16x16x32_f16(av[fi], bf, acc[fi][fj], 0, 0, 0);
      }
    }

    // softmax
    #pragma unroll
    for (int fi = 0; fi < 8; ++fi) {
      #pragma unroll
      for (int r = 0; r < 4; ++r) {
        float mx = -1e30f;
        #pragma unroll
        for (int fj = 0; fj < 4; ++fj) {
          float v = acc[fi][fj][r] + sqv_l[64 * w + 16 * fj + l15];
          acc[fi][fj][r] = v;
          mx = fmaxf(mx, v);
        }
        mx = fmaxf(mx, __shfl_xor(mx, 1, 64));
        mx = fmaxf(mx, __shfl_xor(mx, 2, 64));
        mx = fmaxf(mx, __shfl_xor(mx, 4, 64));
        mx = fmaxf(mx, __shfl_xor(mx, 8, 64));
        if (l15 == 0) red[w][16 * fi + 4 * g + r] = mx;
      }
    }
    __syncthreads();
    if (tid < 128) {
      float m = red[0][tid];
      #pragma unroll
      for (int w2 = 1; w2 < 8; ++w2) m = fmaxf(m, red[w2][tid]);
      mf[tid] = m + scv_l[tid] * 0.0f;
    }
    __syncthreads();
    #pragma unroll
    for (int fi = 0; fi < 8; ++fi) {
      #pragma unroll
      for (int r = 0; r < 4; ++r) {
        float mv = mf[16 * fi + 4 * g + r];
        float s = 0.f;
        #pragma unroll
        for (int fj = 0; fj < 4; ++fj) {
          float p = __expf(acc[fi][fj][r] - mv);
          acc[fi][fj][r] = p;
          s += p;
        }
        s += __shfl_xor(s, 1, 64); s += __shfl_xor(s, 2, 64);
        s += __shfl_xor(s, 4, 64); s += __shfl_xor(s, 8, 64);
        if (l15 == 0) red[w][16 * fi + 4 * g + r] = s;
      }
    }
    __syncthreads();
    if (tid < 128) {
      float s = 0.f;
      #pragma unroll
      for (int w2 = 0; w2 < 8; ++w2) s += red[w2][tid];
      lf[tid] = 1.0f / s;
    }
    __syncthreads();

    // P write (swizzled LDS)
    #pragma unroll
    for (int fi = 0; fi < 8; ++fi) {
      #pragma unroll
      for (int r = 0; r < 4; ++r) {
        int row = 16 * fi + 4 * g + r;
        float inv = lf[row];
        #pragma unroll
        for (int fj = 0; fj < 4; ++fj) {
          *(f16*)(P_b + (((row << 10) + 128 * w + 32 * fj + 2 * l15) ^ ((row & 7) << 4)))
              = (f16)(acc[fi][fj][r] * inv);
        }
      }
    }
    __syncthreads();
  }

  // sink (keeps everything live; covered by real k1's section-0 rewrite)
  int prow = 4 * g;
  float snk = (float)*(const f16*)(P_b + (((prow << 10) + 128 * w + 2 * l15) ^ ((prow & 7) << 4)))
            + acc[0][0][0];
  out[((size_t)(b * CL_ + i0 + (tid >> 2))) * (4 * D_) + (tid & 3)] = snk;
}

// --- pv: phase C MFMAs only (garbage P, real qT gathers) -----------------
__global__ __launch_bounds__(512, 2) void kabl_pv(
    const f16* __restrict__ qT_h, float* __restrict__ out)
{
  __shared__ alignas(16) char smem[142848];
  char* P_b         = smem;
  float (*o_l)[260] = (float (*)[260])(smem);
  const int tid = threadIdx.x;
  const int w = tid >> 6, l = tid & 63, g = l >> 4, l15 = l & 15;
  const int lin = blockIdx.x, xcd = lin & 7, slot = lin >> 3;
  const int b  = xcd * 4 + (slot >> 3);
  const int i0 = (slot & 7) * 128;

  f32x4 o[8][2];
  #pragma unroll
  for (int fi = 0; fi < 8; ++fi) { o[fi][0] = (f32x4){0.f,0.f,0.f,0.f}; o[fi][1] = o[fi][0]; }
  const f16* qTb = qT_h + (size_t)b * D_ * QL_ + (size_t)(32 * w + l15) * QL_ + 8 * g;
  #pragma unroll 1
  for (int rep = 0; rep < 5; ++rep) {
    #pragma unroll
    for (int jt = 0; jt < 16; ++jt) {
      f16x8 qf0 = *(const f16x8*)(qTb + jt * 32);
      f16x8 qf1 = *(const f16x8*)(qTb + 16 * QL_ + jt * 32);
      #pragma unroll
      for (int fi = 0; fi < 8; ++fi) {
        int row = 16 * fi + l15;
        f16x8 pa = *(const f16x8*)(P_b + (((row << 10) + 64 * jt + 16 * g) ^ ((row & 7) << 4)));
        o[fi][0] = __builtin_amdgcn_mfma_f32_16x16x32_f16(pa, qf0, o[fi][0], 0, 0, 0);
        o[fi][1] = __builtin_amdgcn_mfma_f32_16x16x32_f16(pa, qf1, o[fi][1], 0, 0, 0);
      }
    }
    __syncthreads();
  }
  #pragma unroll
  for (int fi = 0; fi < 8; ++fi)
    #pragma unroll
    for (int fd = 0; fd < 2; ++fd)
      #pragma unroll
      for (int r = 0; r < 4; ++r)
        o_l[16 * fi + 4 * g + r][32 * w + 16 * fd + l15] = o[fi][fd][r];
  __syncthreads();
  f32x4 v = *(const f32x4*)(&o_l[tid >> 2][(tid & 3) * 4]);
  out[((size_t)(b * CL_ + i0 + (tid >> 2))) * (4 * D_) + 4 + (tid & 3)]
      = v[0] + v[1] + v[2] + v[3];
}

// --- epi: o_l roundtrip + full 3-section coalesced epilogue --------------
__global__ __launch_bounds__(512, 2) void kabl_epi(
    const float* __restrict__ c, float* __restrict__ out)
{
  __shared__ alignas(16) char smem[142848];
  float (*o_l)[260] = (float (*)[260])(smem);
  const int tid = threadIdx.x;
  const int w = tid >> 6, l = tid & 63, g = l >> 4, l15 = l & 15;
  const int lin = blockIdx.x, xcd = lin & 7, slot = lin >> 3;
  const int b  = xcd * 4 + (slot >> 3);
  const int i0 = (slot & 7) * 128;

  f32x4 o[8][2];
  #pragma unroll
  for (int fi = 0; fi < 8; ++fi) {
    o[fi][0] = (f32x4){(float)tid, 1.f, 2.f, 3.f};
    o[fi][1] = o[fi][0];
  }
  #pragma unroll 1
  for (int rep = 0; rep < 4; ++rep) {
    #pragma unroll
    for (int fi = 0; fi < 8; ++fi)
      #pragma unroll
      for (int fd = 0; fd < 2; ++fd)
        #pragma unroll
        for (int r = 0; r < 4; ++r)
          o_l[16 * fi + 4 * g + r][32 * w + 16 * fd + l15] = o[fi][fd][r] + rep;
    __syncthreads();
    #pragma unroll
    for (int s = 0; s < 16; ++s) {
      int idx = tid + 512 * s;
      int row = idx >> 6;
      int c4  = (((idx & 63) + 16 * rep) & 63) * 4;   // rotate cols per rep
      size_t rowoff = (size_t)(b * CL_ + i0 + row);
      f32x4 c2q = *(const f32x4*)(&o_l[row][c4]);
      f32x4 cv  = *(const f32x4*)(c + rowoff * D_ + c4);
      f32x4 prod;
      prod[0] = cv[0]*c2q[0]; prod[1] = cv[1]*c2q[1];
      prod[2] = cv[2]*c2q[2]; prod[3] = cv[3]*c2q[3];
      float* ob = out + rowoff * (4 * D_) + c4;
      *(f32x4*)(ob)          = cv;
      *(f32x4*)(ob + D_)     = c2q;
      *(f32x4*)(ob + 2 * D_) = prod;
    }
    __syncthreads();
  }
}

// ======================= R7 champion k1_fused ============================
__global__ __launch_bounds__(512, 2) void k1_fused(
    const float* __restrict__ c, const f16* __restrict__ q_h,
    const f16* __restrict__ qT_h, const float* __restrict__ sqv,
    const float* __restrict__ w_c, const float* __restrict__ w_cq,
    float* __restrict__ out, float* __restrict__ mrow)
{
  __shared__ alignas(16) char smem[142848];
  f16 (*cw_t)[264]  = (f16 (*)[264])(smem);
  char* P_b         = smem;
  float (*o_l)[260] = (float (*)[260])(smem);
  float* sqv_l = (float*)(smem + 133120);
  float* wcq_l = (float*)(smem + 135168);
  float* wc_l  = (float*)(smem + 136192);
  float* scv_l = (float*)(smem + 137216);
  float (*red)[128] = (float (*)[128])(smem + 137728);
  float* mf = (float*)(smem + 141824);
  float* lf = (float*)(smem + 142336);

  const int tid = threadIdx.x;
  const int w = tid >> 6, l = tid & 63, g = l >> 4, l15 = l & 15;
  const int lin = blockIdx.x, xcd = lin & 7, slot = lin >> 3;
  const int b  = xcd * 4 + (slot >> 3);
  const int i0 = (slot & 7) * 128;

  if (tid < 256) { wcq_l[tid] = w_cq[tid]; wc_l[tid] = w_c[tid]; }
  sqv_l[tid] = sqv[b * QL_ + tid];
  __syncthreads();

  {
    int row = tid >> 2, seg = tid & 3;
    const float* crow = c + (size_t)(b * CL_ + i0 + row) * D_ + seg * 64;
    float dot = 0.f;
    #pragma unroll
    for (int u = 0; u < 16; ++u) {
      f32x4 v  = *(const f32x4*)(crow + 4 * u);
      f32x4 wv = *(const f32x4*)(wcq_l + seg * 64 + 4 * u);
      f32x4 w2 = *(const f32x4*)(wc_l  + seg * 64 + 4 * u);
      f16x4 h;
      h[0] = (f16)(v[0]*wv[0]); h[1] = (f16)(v[1]*wv[1]);
      h[2] = (f16)(v[2]*wv[2]); h[3] = (f16)(v[3]*wv[3]);
      *(f16x4*)(&cw_t[row][seg * 64 + 4 * u]) = h;
      dot += v[0]*w2[0] + v[1]*w2[1] + v[2]*w2[2] + v[3]*w2[3];
    }
    dot += __shfl_xor(dot, 1, 64); dot += __shfl_xor(dot, 2, 64);
    if (seg == 0) scv_l[row] = dot;
  }
  __syncthreads();

  f32x4 acc[8][4];
  #pragma unroll
  for (int fi = 0; fi < 8; ++fi)
    #pragma unroll
    for (int fj = 0; fj < 4; ++fj)
      acc[fi][fj] = (f32x4){0.f,0.f,0.f,0.f};

  const f16* qb = q_h + (size_t)b * QL_ * D_ + (size_t)(64 * w + l15) * D_ + 8 * g;
  #pragma unroll
  for (int dk = 0; dk < 8; ++dk) {
    f16x8 av[8];
    #pragma unroll
    for (int fi = 0; fi < 8; ++fi)
      av[fi] = *(const f16x8*)(&cw_t[16 * fi + l15][dk * 32 + 8 * g]);
    #pragma unroll
    for (int fj = 0; fj < 4; ++fj) {
      f16x8 bf = *(const f16x8*)(qb + (size_t)(16 * fj) * D_ + dk * 32);
      #pragma unroll
      for (int fi = 0; fi < 8; ++fi)
        acc[fi][fj] = __builtin_amdgcn_mfma_f32_16x16x32_f16(av[fi], bf, acc[fi][fj], 0, 0, 0);
    }
  }

  #pragma unroll
  for (int fi = 0; fi < 8; ++fi) {
    #pragma unroll
    for (int r = 0; r < 4; ++r) {
      float mx = -1e30f;
      #pragma unroll
      for (int fj = 0; fj < 4; ++fj) {
        float v = acc[fi][fj][r] + sqv_l[64 * w + 16 * fj + l15];
        acc[fi][fj][r] = v;
        mx = fmaxf(mx, v);
      }
      mx = fmaxf(mx, __shfl_xor(mx, 1, 64));
      mx = fmaxf(mx, __shfl_xor(mx, 2, 64));
      mx = fmaxf(mx, __shfl_xor(mx, 4, 64));
      mx = fmaxf(mx, __shfl_xor(mx, 8, 64));
      if (l15 == 0) red[w][16 * fi + 4 * g + r] = mx;
    }
  }
  __syncthreads();
  if (tid < 128) {
    float m = red[0][tid];
    #pragma unroll
    for (int w2 = 1; w2 < 8; ++w2) m = fmaxf(m, red[w2][tid]);
    mf[tid] = m;
    mrow[b * CL_ + i0 + tid] = m + scv_l[tid];
  }
  __syncthreads();
  #pragma unroll
  for (int fi = 0; fi < 8; ++fi) {
    #pragma unroll
    for (int r = 0; r < 4; ++r) {
      float mv = mf[16 * fi + 4 * g + r];
      float s = 0.f;
      #pragma unroll
      for (int fj = 0; fj < 4; ++fj) {
        float p = __expf(acc[fi][fj][r] - mv);
        acc[fi][fj][r] = p;
        s += p;
      }
      s += __shfl_xor(s, 1, 64); s += __shfl_xor(s, 2, 64);
      s += __shfl_xor(s, 4, 64); s += __shfl_xor(s, 8, 64);
      if (l15 == 0) red[w][16 * fi + 4 * g + r] = s;
    }
  }
  __syncthreads();
  if (tid < 128) {
    float s = 0.f;
    #pragma unroll
    for (int w2 = 0; w2 < 8; ++w2) s += red[w2][tid];
    lf[tid] = 1.0f / s;
  }
  __syncthreads();

  #pragma unroll
  for (int fi = 0; fi < 8; ++fi) {
    #pragma unroll
    for (int r = 0; r < 4; ++r) {
      int row = 16 * fi + 4 * g + r;
      float inv = lf[row];
      #pragma unroll
      for (int fj = 0; fj < 4; ++fj) {
        *(f16*)(P_b + (((row << 10) + 128 * w + 32 * fj + 2 * l15) ^ ((row & 7) << 4)))
            = (f16)(acc[fi][fj][r] * inv);
      }
    }
  }
  __syncthreads();

  f32x4 o[8][2];
  #pragma unroll
  for (int fi = 0; fi < 8; ++fi) { o[fi][0] = (f32x4){0.f,0.f,0.f,0.f}; o[fi][1] = o[fi][0]; }
  const f16* qTb = qT_h + (size_t)b * D_ * QL_ + (size_t)(32 * w + l15) * QL_ + 8 * g;
  #pragma unroll
  for (int jt = 0; jt < 16; ++jt) {
    f16x8 qf0 = *(const f16x8*)(qTb + jt * 32);
    f16x8 qf1 = *(const f16x8*)(qTb + 16 * QL_ + jt * 32);
    #pragma unroll
    for (int fi = 0; fi < 8; ++fi) {
      int row = 16 * fi + l15;
      f16x8 pa = *(const f16x8*)(P_b + (((row << 10) + 64 * jt + 16 * g) ^ ((row & 7) << 4)));
      o[fi][0] = __builtin_amdgcn_mfma_f32_16x16x32_f16(pa, qf0, o[fi][0], 0, 0, 0);
      o[fi][1] = __builtin_amdgcn_mfma_f32_16x16x32_f16(pa, qf1, o[fi][1], 0, 0, 0);
    }
  }
  __syncthreads();

  #pragma unroll
  for (int fi = 0; fi < 8; ++fi)
    #pragma unroll
    for (int fd = 0; fd < 2; ++fd)
      #pragma unroll
      for (int r = 0; r < 4; ++r)
        o_l[16 * fi + 4 * g + r][32 * w + 16 * fd + l15] = o[fi][fd][r];
  __syncthreads();

  #pragma unroll
  for (int s = 0; s < 16; ++s) {
    int idx = tid + 512 * s;
    int row = idx >> 6, c4 = (idx & 63) * 4;
    size_t rowoff = (size_t)(b * CL_ + i0 + row);
    f32x4 c2q = *(const f32x4*)(&o_l[row][c4]);
    f32x4 cv  = *(const f32x4*)(c + rowoff * D_ + c4);
    f32x4 prod;
    prod[0] = cv[0]*c2q[0]; prod[1] = cv[1]*c2q[1];
    prod[2] = cv[2]*c2q[2]; prod[3] = cv[3]*c2q[3];
    float* ob = out + rowoff * (4 * D_) + c4;
    *(f32x4*)(ob)          = cv;
    *(f32x4*)(ob + D_)     = c2q;
    *(f32x4*)(ob + 2 * D_) = prod;
  }
}

// ------- tails (unchanged champion) --------------------------------------
__global__ __launch_bounds__(256) void k2a_bvec(const float* __restrict__ mrow,
                                                float* __restrict__ bvec) {
  __shared__ float red[256];
  int b = blockIdx.x, tid = threadIdx.x;
  f32x4 v = *(const f32x4*)(mrow + b * CL_ + tid * 4);
  float mx = fmaxf(fmaxf(v[0], v[1]), fmaxf(v[2], v[3]));
  red[tid] = mx;
  __syncthreads();
  for (int s = 128; s > 0; s >>= 1) {
    if (tid < s) red[tid] = fmaxf(red[tid], red[tid + s]);
    __syncthreads();
  }
  float gmx = red[0];
  __syncthreads();
  f32x4 e;
  e[0] = __expf(v[0] - gmx); e[1] = __expf(v[1] - gmx);
  e[2] = __expf(v[2] - gmx); e[3] = __expf(v[3] - gmx);
  red[tid] = e[0] + e[1] + e[2] + e[3];
  __syncthreads();
  for (int s = 128; s > 0; s >>= 1) {
    if (tid < s) red[tid] += red[tid + s];
    __syncthreads();
  }
  float inv = 1.0f / red[0];
  e[0] *= inv; e[1] *= inv; e[2] *= inv; e[3] *= inv;
  *(f32x4*)(bvec + b * CL_ + tid * 4) = e;
}

__global__ __launch_bounds__(256) void k2b_part(const float* __restrict__ c,
                                                const float* __restrict__ bvec,
                                                float* __restrict__ part) {
  __shared__ f32x4 pl[4][64];
  int ch = blockIdx.x, b = blockIdx.y, tid = threadIdx.x;
  int ro = tid >> 6, dl = tid & 63;
  const float* cb = c + ((size_t)b * CL_ + ch * 128) * D_;
  const float* bv = bvec + b * CL_ + ch * 128;
  f32x4 acc = (f32x4){0.f, 0.f, 0.f, 0.f};
  for (int i = ro; i < 128; i += 4) {
    float wgt = bv[i];
    f32x4 v = *(const f32x4*)(cb + (size_t)i * D_ + dl * 4);
    acc[0] += wgt * v[0]; acc[1] += wgt * v[1];
    acc[2] += wgt * v[2]; acc[3] += wgt * v[3];
  }
  pl[ro][dl] = acc;
  __syncthreads();
  if (tid < 64) {
    f32x4 s = (pl[0][tid] + pl[1][tid]) + (pl[2][tid] + pl[3][tid]);
    *(f32x4*)(part + ((size_t)(b * 8 + ch)) * D_ + tid * 4) = s;
  }
}

__global__ __launch_bounds__(256) void k2c_red(const float* __restrict__ part,
                                               float* __restrict__ q2c) {
  int b = blockIdx.x, d = threadIdx.x;
  float s = 0.f;
  #pragma unroll
  for (int ch = 0; ch < 8; ++ch) s += part[((size_t)(b * 8 + ch)) * D_ + d];
  q2c[b * D_ + d] = s;
}

__global__ __launch_bounds__(256) void k3_tail(const float* __restrict__ c,
                                               const float* __restrict__ q2c,
                                               float* __restrict__ out) {
  size_t idx = (size_t)blockIdx.x * 256 + threadIdx.x;
  int b   = (int)(idx >> 16);
  int rem = (int)(idx & 65535);
  int i = rem >> 6, d4 = (rem & 63) * 4;
  f32x4 cv = *(const f32x4*)(c + (size_t)(b * CL_ + i) * D_ + d4);
  f32x4 gv = *(const f32x4*)(q2c + b * D_ + d4);
  f32x4 r;
  r[0] = cv[0]*gv[0]; r[1] = cv[1]*gv[1]; r[2] = cv[2]*gv[2]; r[3] = cv[3]*gv[3];
  *(f32x4*)(out + (size_t)(b * CL_ + i) * (4 * D_) + 3 * D_ + d4) = r;
}

extern "C" void kernel_launch(void* const* d_in, const int* in_sizes, int n_in,
                              void* d_out, int out_size, void* d_ws, size_t ws_size,
                              hipStream_t stream) {
  const float* c    = (const float*)d_in[0];
  const float* q    = (const float*)d_in[1];
  const float* w_c  = (const float*)d_in[2];
  const float* w_q  = (const float*)d_in[4];
  const float* w_cq = (const float*)d_in[6];
  float* out = (float*)d_out;
  char* ws = (char*)d_ws;
  f16*   q_h  = (f16*)ws;
  f16*   qT_h = (f16*)(ws + 8388608);
  float* sqv  = (float*)(ws + 16777216);
  float* mrow = (float*)(ws + 16842752);
  float* bvec = (float*)(ws + 16973824);
  float* part = (float*)(ws + 17104896);
  float* q2c  = (float*)(ws + 17367040);

  hipLaunchKernelGGL(k0_prep,    dim3(8, 32),  dim3(256), 0, stream,
                     q, w_q, q_h, qT_h, sqv);
  // ---- ablation dispatches (timing probes; outputs rewritten below) ----
  hipLaunchKernelGGL(kabl_front, dim3(256),    dim3(512), 0, stream,
                     c, q_h, sqv, w_c, w_cq, out);
  hipLaunchKernelGGL(kabl_pv,    dim3(256),    dim3(512), 0, stream,
                     qT_h, out);
  hipLaunchKernelGGL(kabl_epi,   dim3(256),    dim3(512), 0, stream,
                     c, out);
  // ---- real pipeline (R7 champion) -------------------------------------
  hipLaunchKernelGGL(k1_fused,   dim3(256),    dim3(512), 0, stream,
                     c, q_h, qT_h, sqv, w_c, w_cq, out, mrow);
  hipLaunchKernelGGL(k2a_bvec,   dim3(32),     dim3(256), 0, stream, mrow, bvec);
  hipLaunchKernelGGL(k2b_part,   dim3(8, 32),  dim3(256), 0, stream, c, bvec, part);
  hipLaunchKernelGGL(k2c_red,    dim3(32),     dim3(256), 0, stream, part, q2c);
  hipLaunchKernelGGL(k3_tail,    dim3(8192),   dim3(256), 0, stream, c, q2c, out);
}

// Round 15
// 95.093 us; speedup vs baseline: 6.8072x; 6.8072x over previous
//
#include <hip/hip_runtime.h>

#define B_  32
#define CL_ 1024
#define QL_ 512
#define D_  256

typedef _Float16 f16;
typedef __attribute__((ext_vector_type(2))) _Float16 f16x2;
typedef __attribute__((ext_vector_type(4))) _Float16 f16x4;
typedef __attribute__((ext_vector_type(8))) _Float16 f16x8;
typedef __attribute__((ext_vector_type(4))) float    f32x4;

// ------- K0: q -> fragment-ordered buffers qF/qTF + sqv ------------------
// qF[(b*8+J)*32 + dk*4+fj][l][8]  : bf fragment for phase A (j=64J+16fj+l15,
//                                   elems d = dk*32+8g+e)
// qTF[((b*8+W)*16+jt)*2+fd][l][8] : qT fragment for phase C (d=32W+16fd+l15,
//                                   elems j = jt*32+8g+e)
// Consumer loads become base + l*16B: perfectly coalesced, zero line-ampl.
__global__ __launch_bounds__(256) void k0_prep(const float* __restrict__ q,
                                               const float* __restrict__ w_q,
                                               f16* __restrict__ qF,
                                               f16* __restrict__ qTF,
                                               float* __restrict__ sqv) {
  __shared__ f16 q_l[64][258];                 // +2 pad
  int b = blockIdx.y, J = blockIdx.x, j0 = J * 64, tid = threadIdx.x;
  int r = tid >> 2, seg = tid & 3;
  const float* qrow = q + ((size_t)(b * QL_ + j0 + r)) * D_ + seg * 64;
  float dot = 0.f;
  #pragma unroll
  for (int u = 0; u < 16; ++u) {
    f32x4 v  = *(const f32x4*)(qrow + 4 * u);
    f32x4 wv = *(const f32x4*)(w_q + seg * 64 + 4 * u);
    f16x4 h;
    h[0] = (f16)v[0]; h[1] = (f16)v[1]; h[2] = (f16)v[2]; h[3] = (f16)v[3];
    *(f16x4*)(&q_l[r][seg * 64 + 4 * u]) = h;
    dot += v[0]*wv[0] + v[1]*wv[1] + v[2]*wv[2] + v[3]*wv[3];
  }
  dot += __shfl_xor(dot, 1, 64);
  dot += __shfl_xor(dot, 2, 64);
  if (seg == 0) sqv[b * QL_ + j0 + r] = dot;
  __syncthreads();

  const int ww = tid >> 6, l = tid & 63, g = l >> 4, l15 = l & 15;
  // qF emission: 32 tasks (dk,fj); contiguous 1KB per wave-store
  f16* qFb = qF + ((size_t)(b * 8 + J)) * 16384;
  #pragma unroll
  for (int t = 0; t < 8; ++t) {
    int task = ww * 8 + t;            // 0..31
    int dk = task >> 2, fj = task & 3;
    f16x8 v = *(const f16x8*)(&q_l[16 * fj + l15][dk * 32 + 8 * g]);
    *(f16x8*)(qFb + ((size_t)task * 64 + l) * 8) = v;
  }
  // qTF emission: 32 tasks (W,jtl,fd); transpose gather from LDS
  #pragma unroll
  for (int t = 0; t < 8; ++t) {
    int task = ww * 8 + t;            // 0..31
    int W = task >> 2, jtl = (task >> 1) & 1, fd = task & 1;
    f16x8 v;
    #pragma unroll
    for (int e = 0; e < 8; ++e)
      v[e] = q_l[32 * jtl + 8 * g + e][32 * W + 16 * fd + l15];
    *(f16x8*)(qTF + ((((size_t)(b * 8 + W) * 16 + (2 * J + jtl)) * 2 + fd) * 64 + l) * 8) = v;
  }
}

// ------- K1 fused, BM=128 (R7 champion) with fragment-ordered loads ------
__global__ __launch_bounds__(512, 2) void k1_fused(
    const float* __restrict__ c, const f16* __restrict__ qF,
    const f16* __restrict__ qTF, const float* __restrict__ sqv,
    const float* __restrict__ w_c, const float* __restrict__ w_cq,
    float* __restrict__ out, float* __restrict__ mrow)
{
  __shared__ alignas(16) char smem[142848];
  f16 (*cw_t)[264]  = (f16 (*)[264])(smem);          // 67584 B (phase A)
  char* P_b         = smem;                          // 131072 B swz (B/C)
  float (*o_l)[260] = (float (*)[260])(smem);        // 133120 B (epilogue)
  float* sqv_l = (float*)(smem + 133120);
  float* wcq_l = (float*)(smem + 135168);
  float* wc_l  = (float*)(smem + 136192);
  float* scv_l = (float*)(smem + 137216);
  float (*red)[128] = (float (*)[128])(smem + 137728);
  float* mf = (float*)(smem + 141824);
  float* lf = (float*)(smem + 142336);

  const int tid = threadIdx.x;
  const int w = tid >> 6, l = tid & 63, g = l >> 4, l15 = l & 15;
  const int lin = blockIdx.x, xcd = lin & 7, slot = lin >> 3;
  const int b  = xcd * 4 + (slot >> 3);              // 4 batches per XCD
  const int i0 = (slot & 7) * 128;

  if (tid < 256) { wcq_l[tid] = w_cq[tid]; wc_l[tid] = w_c[tid]; }
  sqv_l[tid] = sqv[b * QL_ + tid];
  __syncthreads();

  // ---- stage cw_t = f16(c * w_cq) (128 rows); scv = c . w_c ------------
  {
    int row = tid >> 2, seg = tid & 3;
    const float* crow = c + (size_t)(b * CL_ + i0 + row) * D_ + seg * 64;
    float dot = 0.f;
    #pragma unroll
    for (int u = 0; u < 16; ++u) {
      f32x4 v  = *(const f32x4*)(crow + 4 * u);
      f32x4 wv = *(const f32x4*)(wcq_l + seg * 64 + 4 * u);
      f32x4 w2 = *(const f32x4*)(wc_l  + seg * 64 + 4 * u);
      f16x4 h;
      h[0] = (f16)(v[0]*wv[0]); h[1] = (f16)(v[1]*wv[1]);
      h[2] = (f16)(v[2]*wv[2]); h[3] = (f16)(v[3]*wv[3]);
      *(f16x4*)(&cw_t[row][seg * 64 + 4 * u]) = h;
      dot += v[0]*w2[0] + v[1]*w2[1] + v[2]*w2[2] + v[3]*w2[3];
    }
    dot += __shfl_xor(dot, 1, 64); dot += __shfl_xor(dot, 2, 64);
    if (seg == 0) scv_l[row] = dot;
  }
  __syncthreads();

  // ---- Phase A: wave w owns j-slice [64w,64w+64); fragment-stream loads -
  f32x4 acc[8][4];
  #pragma unroll
  for (int fi = 0; fi < 8; ++fi)
    #pragma unroll
    for (int fj = 0; fj < 4; ++fj)
      acc[fi][fj] = (f32x4){0.f,0.f,0.f,0.f};

  const f16* qFb = qF + ((size_t)(b * 8 + w)) * 16384;   // this wave's 32KB
  #pragma unroll
  for (int dk = 0; dk < 8; ++dk) {
    f16x8 av[8];
    #pragma unroll
    for (int fi = 0; fi < 8; ++fi)
      av[fi] = *(const f16x8*)(&cw_t[16 * fi + l15][dk * 32 + 8 * g]);
    #pragma unroll
    for (int fj = 0; fj < 4; ++fj) {
      f16x8 bf = *(const f16x8*)(qFb + (((size_t)dk * 4 + fj) * 64 + l) * 8);
      #pragma unroll
      for (int fi = 0; fi < 8; ++fi)
        acc[fi][fj] = __builtin_amdgcn_mfma_f32_16x16x32_f16(av[fi], bf, acc[fi][fj], 0, 0, 0);
    }
  }

  // ---- Phase B: softmax over j ----
  #pragma unroll
  for (int fi = 0; fi < 8; ++fi) {
    #pragma unroll
    for (int r = 0; r < 4; ++r) {
      float mx = -1e30f;
      #pragma unroll
      for (int fj = 0; fj < 4; ++fj) {
        float v = acc[fi][fj][r] + sqv_l[64 * w + 16 * fj + l15];
        acc[fi][fj][r] = v;
        mx = fmaxf(mx, v);
      }
      mx = fmaxf(mx, __shfl_xor(mx, 1, 64));
      mx = fmaxf(mx, __shfl_xor(mx, 2, 64));
      mx = fmaxf(mx, __shfl_xor(mx, 4, 64));
      mx = fmaxf(mx, __shfl_xor(mx, 8, 64));
      if (l15 == 0) red[w][16 * fi + 4 * g + r] = mx;
    }
  }
  __syncthreads();
  if (tid < 128) {
    float m = red[0][tid];
    #pragma unroll
    for (int w2 = 1; w2 < 8; ++w2) m = fmaxf(m, red[w2][tid]);
    mf[tid] = m;
    mrow[b * CL_ + i0 + tid] = m + scv_l[tid];
  }
  __syncthreads();
  #pragma unroll
  for (int fi = 0; fi < 8; ++fi) {
    #pragma unroll
    for (int r = 0; r < 4; ++r) {
      float mv = mf[16 * fi + 4 * g + r];
      float s = 0.f;
      #pragma unroll
      for (int fj = 0; fj < 4; ++fj) {
        float p = __expf(acc[fi][fj][r] - mv);
        acc[fi][fj][r] = p;
        s += p;
      }
      s += __shfl_xor(s, 1, 64); s += __shfl_xor(s, 2, 64);
      s += __shfl_xor(s, 4, 64); s += __shfl_xor(s, 8, 64);
      if (l15 == 0) red[w][16 * fi + 4 * g + r] = s;
    }
  }
  __syncthreads();
  if (tid < 128) {
    float s = 0.f;
    #pragma unroll
    for (int w2 = 0; w2 < 8; ++w2) s += red[w2][tid];
    lf[tid] = 1.0f / s;
  }
  __syncthreads();   // cw_t dead; P_b may overwrite

  // ---- write normalized P into swizzled LDS tile -----------------------
  #pragma unroll
  for (int fi = 0; fi < 8; ++fi) {
    #pragma unroll
    for (int r = 0; r < 4; ++r) {
      int row = 16 * fi + 4 * g + r;
      float inv = lf[row];
      #pragma unroll
      for (int fj = 0; fj < 4; ++fj) {
        *(f16*)(P_b + (((row << 10) + 128 * w + 32 * fj + 2 * l15) ^ ((row & 7) << 4)))
            = (f16)(acc[fi][fj][r] * inv);
      }
    }
  }
  __syncthreads();   // P visible to all waves

  // ---- Phase C: c2q = P @ qT; wave w owns d-slice; fragment streams ----
  f32x4 o[8][2];
  #pragma unroll
  for (int fi = 0; fi < 8; ++fi) { o[fi][0] = (f32x4){0.f,0.f,0.f,0.f}; o[fi][1] = o[fi][0]; }
  const f16* qTFb = qTF + ((size_t)(b * 8 + w)) * 16384;  // this wave's 32KB
  #pragma unroll
  for (int jt = 0; jt < 16; ++jt) {
    f16x8 qf0 = *(const f16x8*)(qTFb + (((size_t)jt * 2 + 0) * 64 + l) * 8);
    f16x8 qf1 = *(const f16x8*)(qTFb + (((size_t)jt * 2 + 1) * 64 + l) * 8);
    #pragma unroll
    for (int fi = 0; fi < 8; ++fi) {
      int row = 16 * fi + l15;
      f16x8 pa = *(const f16x8*)(P_b + (((row << 10) + 64 * jt + 16 * g) ^ ((row & 7) << 4)));
      o[fi][0] = __builtin_amdgcn_mfma_f32_16x16x32_f16(pa, qf0, o[fi][0], 0, 0, 0);
      o[fi][1] = __builtin_amdgcn_mfma_f32_16x16x32_f16(pa, qf1, o[fi][1], 0, 0, 0);
    }
  }
  __syncthreads();   // all P reads done before o_l overwrites

  #pragma unroll
  for (int fi = 0; fi < 8; ++fi)
    #pragma unroll
    for (int fd = 0; fd < 2; ++fd)
      #pragma unroll
      for (int r = 0; r < 4; ++r)
        o_l[16 * fi + 4 * g + r][32 * w + 16 * fd + l15] = o[fi][fd][r];
  __syncthreads();

  // ---- Epilogue: coalesced f32x4 stores of out[0:3D] -------------------
  #pragma unroll
  for (int s = 0; s < 16; ++s) {
    int idx = tid + 512 * s;                 // 128 rows x 64 f32x4
    int row = idx >> 6, c4 = (idx & 63) * 4;
    size_t rowoff = (size_t)(b * CL_ + i0 + row);
    f32x4 c2q = *(const f32x4*)(&o_l[row][c4]);
    f32x4 cv  = *(const f32x4*)(c + rowoff * D_ + c4);
    f32x4 prod;
    prod[0] = cv[0]*c2q[0]; prod[1] = cv[1]*c2q[1];
    prod[2] = cv[2]*c2q[2]; prod[3] = cv[3]*c2q[3];
    float* ob = out + rowoff * (4 * D_) + c4;
    *(f32x4*)(ob)          = cv;
    *(f32x4*)(ob + D_)     = c2q;
    *(f32x4*)(ob + 2 * D_) = prod;
  }
}

// ------- K2a: bvec[b,:] = softmax_i(mrow[b,:]) ---------------------------
__global__ __launch_bounds__(256) void k2a_bvec(const float* __restrict__ mrow,
                                                float* __restrict__ bvec) {
  __shared__ float red[256];
  int b = blockIdx.x, tid = threadIdx.x;
  f32x4 v = *(const f32x4*)(mrow + b * CL_ + tid * 4);
  float mx = fmaxf(fmaxf(v[0], v[1]), fmaxf(v[2], v[3]));
  red[tid] = mx;
  __syncthreads();
  for (int s = 128; s > 0; s >>= 1) {
    if (tid < s) red[tid] = fmaxf(red[tid], red[tid + s]);
    __syncthreads();
  }
  float gmx = red[0];
  __syncthreads();
  f32x4 e;
  e[0] = __expf(v[0] - gmx); e[1] = __expf(v[1] - gmx);
  e[2] = __expf(v[2] - gmx); e[3] = __expf(v[3] - gmx);
  red[tid] = e[0] + e[1] + e[2] + e[3];
  __syncthreads();
  for (int s = 128; s > 0; s >>= 1) {
    if (tid < s) red[tid] += red[tid + s];
    __syncthreads();
  }
  float inv = 1.0f / red[0];
  e[0] *= inv; e[1] *= inv; e[2] *= inv; e[3] *= inv;
  *(f32x4*)(bvec + b * CL_ + tid * 4) = e;
}

// ------- K2b: part[b,ch,:] = sum_{i in chunk} bvec[i] * c[i,:] -----------
__global__ __launch_bounds__(256) void k2b_part(const float* __restrict__ c,
                                                const float* __restrict__ bvec,
                                                float* __restrict__ part) {
  __shared__ f32x4 pl[4][64];
  int ch = blockIdx.x, b = blockIdx.y, tid = threadIdx.x;
  int ro = tid >> 6, dl = tid & 63;
  const float* cb = c + ((size_t)b * CL_ + ch * 128) * D_;
  const float* bv = bvec + b * CL_ + ch * 128;
  f32x4 acc = (f32x4){0.f, 0.f, 0.f, 0.f};
  for (int i = ro; i < 128; i += 4) {
    float wgt = bv[i];
    f32x4 v = *(const f32x4*)(cb + (size_t)i * D_ + dl * 4);
    acc[0] += wgt * v[0]; acc[1] += wgt * v[1];
    acc[2] += wgt * v[2]; acc[3] += wgt * v[3];
  }
  pl[ro][dl] = acc;
  __syncthreads();
  if (tid < 64) {
    f32x4 s = (pl[0][tid] + pl[1][tid]) + (pl[2][tid] + pl[3][tid]);
    *(f32x4*)(part + ((size_t)(b * 8 + ch)) * D_ + tid * 4) = s;
  }
}

// ------- K2c: q2c[b,:] = sum_ch part[b,ch,:] -----------------------------
__global__ __launch_bounds__(256) void k2c_red(const float* __restrict__ part,
                                               float* __restrict__ q2c) {
  int b = blockIdx.x, d = threadIdx.x;
  float s = 0.f;
  #pragma unroll
  for (int ch = 0; ch < 8; ++ch) s += part[((size_t)(b * 8 + ch)) * D_ + d];
  q2c[b * D_ + d] = s;
}

// ------- K3: out[3D:4D] = c * q2c (broadcast) ----------------------------
__global__ __launch_bounds__(256) void k3_tail(const float* __restrict__ c,
                                               const float* __restrict__ q2c,
                                               float* __restrict__ out) {
  size_t idx = (size_t)blockIdx.x * 256 + threadIdx.x;
  int b   = (int)(idx >> 16);
  int rem = (int)(idx & 65535);
  int i = rem >> 6, d4 = (rem & 63) * 4;
  f32x4 cv = *(const f32x4*)(c + (size_t)(b * CL_ + i) * D_ + d4);
  f32x4 gv = *(const f32x4*)(q2c + b * D_ + d4);
  f32x4 r;
  r[0] = cv[0]*gv[0]; r[1] = cv[1]*gv[1]; r[2] = cv[2]*gv[2]; r[3] = cv[3]*gv[3];
  *(f32x4*)(out + (size_t)(b * CL_ + i) * (4 * D_) + 3 * D_ + d4) = r;
}

extern "C" void kernel_launch(void* const* d_in, const int* in_sizes, int n_in,
                              void* d_out, int out_size, void* d_ws, size_t ws_size,
                              hipStream_t stream) {
  const float* c    = (const float*)d_in[0];
  const float* q    = (const float*)d_in[1];
  const float* w_c  = (const float*)d_in[2];
  const float* w_q  = (const float*)d_in[4];
  const float* w_cq = (const float*)d_in[6];
  float* out = (float*)d_out;
  char* ws = (char*)d_ws;
  f16*   qF   = (f16*)ws;                       //  8,388,608 B (phase-A frags)
  f16*   qTF  = (f16*)(ws + 8388608);           //  8,388,608 B (phase-C frags)
  float* sqv  = (float*)(ws + 16777216);        //     65,536 B
  float* mrow = (float*)(ws + 16842752);        //    131,072 B
  float* bvec = (float*)(ws + 16973824);        //    131,072 B
  float* part = (float*)(ws + 17104896);        //    262,144 B
  float* q2c  = (float*)(ws + 17367040);        //     32,768 B

  hipLaunchKernelGGL(k0_prep,  dim3(8, 32),  dim3(256), 0, stream,
                     q, w_q, qF, qTF, sqv);
  hipLaunchKernelGGL(k1_fused, dim3(256),    dim3(512), 0, stream,
                     c, qF, qTF, sqv, w_c, w_cq, out, mrow);
  hipLaunchKernelGGL(k2a_bvec, dim3(32),     dim3(256), 0, stream, mrow, bvec);
  hipLaunchKernelGGL(k2b_part, dim3(8, 32),  dim3(256), 0, stream, c, bvec, part);
  hipLaunchKernelGGL(k2c_red,  dim3(32),     dim3(256), 0, stream, part, q2c);
  hipLaunchKernelGGL(k3_tail,  dim3(8192),   dim3(256), 0, stream, c, q2c, out);
}